// Round 11
// baseline (650.909 us; speedup 1.0000x reference)
//
#include <hip/hip_runtime.h>

using u16 = unsigned short;
typedef short bf8 __attribute__((ext_vector_type(8)));
typedef float f4 __attribute__((ext_vector_type(4)));

constexpr int Bb = 8;
constexpr int Nn = 16384;
constexpr int Kk = 128;
constexpr int Cc = 128;
constexpr int Ll = 4;
constexpr int SPLIT = 32;

__device__ __forceinline__ float b2f(u16 u) {
    union { unsigned int i; float f; } v; v.i = ((unsigned int)u) << 16; return v.f;
}
__device__ __forceinline__ u16 f2b(float f) {
    union { float f; unsigned int i; } v; v.f = f;
    unsigned int i = v.i;
    return (u16)((i + 0x7fffu + ((i >> 16) & 1u)) >> 16);
}
__device__ __forceinline__ float gelu_f(float x) {
    return 0.5f * x * (1.0f + erff(x * 0.70710678118654752f));
}

__device__ __forceinline__ void gload16(const void* g, const u16* l) {
    __builtin_amdgcn_global_load_lds(
        (const __attribute__((address_space(1))) void*)g,
        (__attribute__((address_space(3))) void*)(u16*)l, 16, 0, 0);
}

// ---- dtype detection + input normalization ----
__global__ void detect_kernel(const unsigned int* __restrict__ maskw, int* __restrict__ flag) {
    if (threadIdx.x == 0 && blockIdx.x == 0)
        *flag = ((maskw[0] & 0xFFFFu) != 0u) ? 1 : 0;   // 1 = inputs are bf16
}

struct SegTable {
    const void* src[16];
    u16* dst[16];
    int count[16];
};

__global__ __launch_bounds__(256) void convert_kernel(SegTable t, const int* __restrict__ flag) {
    const int f = *flag;
    const int stride = gridDim.x * 256;
    for (int seg = 0; seg < 16; ++seg) {
        const int cnt = t.count[seg];
        const void* s = t.src[seg];
        u16* d = t.dst[seg];
        for (int i = blockIdx.x * 256 + threadIdx.x; i < cnt; i += stride) {
            d[i] = f ? ((const u16*)s)[i] : f2b(((const float*)s)[i]);
        }
    }
}

// prep_nk: fused bases_nk (bigB) + fc0_nk (hA, hw_cn) — identical grids,
// independent inputs/outputs; bodies verbatim. Saves one launch boundary.
__global__ __launch_bounds__(256) void prep_nk(
    const u16* __restrict__ nodes, const u16* __restrict__ modes,
    const u16* __restrict__ mask, u16* __restrict__ bigB,
    const u16* __restrict__ x, const u16* __restrict__ fc0_w,
    const u16* __restrict__ fc0_b, const u16* __restrict__ wn,
    u16* __restrict__ hA, u16* __restrict__ hw_cn) {
    int t = threadIdx.x;
    int nl = t >> 2, kp = t & 3;
    int n = blockIdx.x * 64 + nl, b = blockIdx.y;
    // ---- bases part ----
    {
        float nx = b2f(nodes[((size_t)(b * Nn + n)) * 2]);
        float ny = b2f(nodes[((size_t)(b * Nn + n)) * 2 + 1]);
        float mk = b2f(mask[b * Nn + n]);
        u16 cb[32] __attribute__((aligned(16)));
        u16 sb[32] __attribute__((aligned(16)));
        #pragma unroll
        for (int j = 0; j < 32; j++) {
            int k = kp * 32 + j;
            float m0 = b2f(modes[k * 2]), m1 = b2f(modes[k * 2 + 1]);
            float tt = nx * m0 + ny * m1;
            float sv, cv;
            __sincosf(tt, &sv, &cv);
            cb[j] = f2b(cv * mk);
            sb[j] = f2b(sv * mk);
        }
        u16* row = bigB + ((size_t)b * Nn + n) * 256;
        #pragma unroll
        for (int i = 0; i < 4; i++) {
            *(uint4*)(row + kp * 32 + i * 8)       = *(const uint4*)(cb + i * 8);
            *(uint4*)(row + 128 + kp * 32 + i * 8) = *(const uint4*)(sb + i * 8);
        }
    }
    // ---- fc0 part ----
    {
        const u16* xp = x + ((size_t)(b * Nn + n)) * 3;
        float x0v = b2f(xp[0]), x1v = b2f(xp[1]), x2v = b2f(xp[2]);
        float wv = b2f(wn[b * Nn + n]);
        u16 hb[32] __attribute__((aligned(16)));
        #pragma unroll
        for (int j = 0; j < 32; j++) {
            int c = kp * 32 + j;
            float acc = b2f(fc0_b[c]);
            acc += x0v * b2f(fc0_w[0 * Cc + c]);
            acc += x1v * b2f(fc0_w[1 * Cc + c]);
            acc += x2v * b2f(fc0_w[2 * Cc + c]);
            hb[j] = f2b(acc);
            hw_cn[((size_t)(b * Cc + c)) * Nn + n] = f2b(acc * wv);
        }
        u16* row = hA + ((size_t)b * Nn + n) * 128 + kp * 32;
        #pragma unroll
        for (int i = 0; i < 4; i++) *(uint4*)(row + i * 8) = *(const uint4*)(hb + i * 8);
    }
}

// one-shot all layers: wcT/wsT[l][k][o][i] bf16 from raw [l][i][o][k]; w0T[l][o][i]
__global__ __launch_bounds__(256) void transpose_w(
    const void* __restrict__ wcraw, const void* __restrict__ wsraw,
    const u16* __restrict__ w0n,
    u16* __restrict__ wcT, u16* __restrict__ wsT, u16* __restrict__ w0T,
    const int* __restrict__ flag) {
    __shared__ u16 tile[128][136];
    int o = blockIdx.x, l = blockIdx.y, t = threadIdx.x;
    const int f = *flag;
    if (o == 128) {
        int i = t >> 1, oh = (t & 1) * 64;
        #pragma unroll
        for (int j = 0; j < 64; j += 8)
            *(uint4*)&tile[i][oh + j] = *(const uint4*)(w0n + ((size_t)(l * 128 + i)) * 128 + oh + j);
        __syncthreads();
        int o2 = t >> 1, ih = (t & 1) * 64;
        u16 buf[64] __attribute__((aligned(16)));
        #pragma unroll
        for (int j = 0; j < 64; j++) buf[j] = tile[ih + j][o2];
        #pragma unroll
        for (int j = 0; j < 64; j += 8)
            *(uint4*)(w0T + ((size_t)(l * 128 + o2)) * 128 + ih + j) = *(const uint4*)(buf + j);
        return;
    }
    for (int wsel = 0; wsel < 2; wsel++) {
        if (wsel) __syncthreads();
        const void* raw = wsel ? wsraw : wcraw;
        u16* dst = wsel ? wsT : wcT;
        int i = t >> 1, kh = (t & 1) * 64;
        size_t base = (((size_t)(l * 128 + i)) * 128 + o) * 128 + kh;
        if (f) {
            #pragma unroll
            for (int j = 0; j < 64; j += 8)
                *(uint4*)&tile[i][kh + j] = *(const uint4*)((const u16*)raw + base + j);
        } else {
            #pragma unroll
            for (int j = 0; j < 64; j += 4) {
                float4 v = *(const float4*)((const float*)raw + base + j);
                u16 o4[4] __attribute__((aligned(8))) = { f2b(v.x), f2b(v.y), f2b(v.z), f2b(v.w) };
                *(unsigned long long*)&tile[i][kh + j] = *(const unsigned long long*)o4;
            }
        }
        __syncthreads();
        int k = t >> 1, ih = (t & 1) * 64;
        u16 buf[64] __attribute__((aligned(16)));
        #pragma unroll
        for (int j = 0; j < 64; j++) buf[j] = tile[ih + j][k];
        #pragma unroll
        for (int j = 0; j < 64; j += 8)
            *(uint4*)(dst + (((size_t)(l * 128 + k)) * 128 + o) * 128 + ih + j) = *(const uint4*)(buf + j);
    }
}

// MFMA projection v7: grid (32, 8) = 256 blocks x 512 threads (8 waves).
// Wave w owns k-slice w*16+lo (8 waves cover all 128 modes, kt-loop gone) and
// ALL 8 c-tiles -> each trig value computed ONCE per dispatch (was 2x via the
// ch-grid). A rows read identically by all waves (L1 broadcast); external
// traffic unchanged. Bitwise-identical accumulation per (k,c,s): same angle
// expression, same js order, same write addresses. SPLIT unchanged.
__global__ __launch_bounds__(512) void proj_mfma(
    const u16* __restrict__ hw, const u16* __restrict__ nodes,
    const u16* __restrict__ modes, const u16* __restrict__ mask,
    u16* __restrict__ pxc, u16* __restrict__ pps) {
    int s = blockIdx.x, b = blockIdx.y;
    int w = threadIdx.x >> 6, lane = threadIdx.x & 63;
    int lo = lane & 15, q = lane >> 4;
    int n0 = s * 512;
    int kmode = w * 16 + lo;
    float m0 = b2f(modes[kmode * 2]), m1 = b2f(modes[kmode * 2 + 1]);
    const u16* ap[8];
    #pragma unroll
    for (int ct = 0; ct < 8; ct++)
        ap[ct] = hw + ((size_t)(b * Cc) + ct * 16 + lo) * Nn + n0 + q * 8;
    const u16* np = nodes + ((size_t)(b * Nn) + n0 + q * 8) * 2;
    const u16* mp = mask + (size_t)b * Nn + n0 + q * 8;
    f4 aC[8] = {}, aS[8] = {};
    for (int js = 0; js < 16; js++) {
        int off = js * 32;
        uint4 nq0 = *(const uint4*)(np + off * 2);
        uint4 nq1 = *(const uint4*)(np + off * 2 + 8);
        uint4 mq  = *(const uint4*)(mp + off);
        float xs[8], ys[8], mk[8];
        xs[0] = b2f(nq0.x & 0xffffu); ys[0] = b2f(nq0.x >> 16);
        xs[1] = b2f(nq0.y & 0xffffu); ys[1] = b2f(nq0.y >> 16);
        xs[2] = b2f(nq0.z & 0xffffu); ys[2] = b2f(nq0.z >> 16);
        xs[3] = b2f(nq0.w & 0xffffu); ys[3] = b2f(nq0.w >> 16);
        xs[4] = b2f(nq1.x & 0xffffu); ys[4] = b2f(nq1.x >> 16);
        xs[5] = b2f(nq1.y & 0xffffu); ys[5] = b2f(nq1.y >> 16);
        xs[6] = b2f(nq1.z & 0xffffu); ys[6] = b2f(nq1.z >> 16);
        xs[7] = b2f(nq1.w & 0xffffu); ys[7] = b2f(nq1.w >> 16);
        mk[0] = b2f(mq.x & 0xffffu);  mk[1] = b2f(mq.x >> 16);
        mk[2] = b2f(mq.y & 0xffffu);  mk[3] = b2f(mq.y >> 16);
        mk[4] = b2f(mq.z & 0xffffu);  mk[5] = b2f(mq.z >> 16);
        mk[6] = b2f(mq.w & 0xffffu);  mk[7] = b2f(mq.w >> 16);
        u16 cf[8] __attribute__((aligned(16)));
        u16 sf[8] __attribute__((aligned(16)));
        #pragma unroll
        for (int j = 0; j < 8; j++) {
            float tt = xs[j] * m0 + ys[j] * m1;
            float sv, cv;
            __sincosf(tt, &sv, &cv);
            cf[j] = f2b(cv * mk[j]);
            sf[j] = f2b(sv * mk[j]);
        }
        bf8 cv8 = *(const bf8*)cf;
        bf8 sv8 = *(const bf8*)sf;
        #pragma unroll
        for (int ct = 0; ct < 8; ct++) {
            bf8 av = *(const bf8*)(ap[ct] + off);
            aC[ct] = __builtin_amdgcn_mfma_f32_16x16x32_bf16(av, cv8, aC[ct], 0, 0, 0);
            aS[ct] = __builtin_amdgcn_mfma_f32_16x16x32_bf16(av, sv8, aS[ct], 0, 0, 0);
        }
    }
    size_t base = ((size_t)(b * SPLIT + s)) * 16384 + (size_t)kmode * 128;
    #pragma unroll
    for (int ct = 0; ct < 8; ct++) {
        int c0 = ct * 16 + q * 4;
        u16 pc[4] __attribute__((aligned(8)));
        u16 pssv[4] __attribute__((aligned(8)));
        #pragma unroll
        for (int r = 0; r < 4; r++) { pc[r] = f2b(aC[ct][r]); pssv[r] = f2b(aS[ct][r]); }
        *(uint2*)&pxc[base + c0] = *(const uint2*)pc;
        *(uint2*)&pps[base + c0] = *(const uint2*)pssv;
    }
}

// reduce v2: blocks 0..511 = bf16 partial sum over s (unchanged math);
// blocks 512..1535 = the old x0_kernel verbatim (x0[b,c] = sum_n hw*mask).
__global__ __launch_bounds__(256) void reduce_kernel(
    const u16* __restrict__ pxc, const u16* __restrict__ pps,
    u16* __restrict__ xcT, u16* __restrict__ psT,
    const u16* __restrict__ hw, const u16* __restrict__ mask,
    u16* __restrict__ x0b) {
    __shared__ float red[4];
    if (blockIdx.x >= 512) {
        int xb = blockIdx.x - 512;
        int c = xb & 127, b = xb >> 7;
        const u16* row = hw + ((size_t)(b * Cc + c)) * Nn;
        const u16* mrow = mask + (size_t)b * Nn;
        float acc = 0.f;
        for (int n = threadIdx.x; n < Nn; n += 256) acc += b2f(row[n]) * b2f(mrow[n]);
        for (int off = 32; off; off >>= 1) acc += __shfl_down(acc, off, 64);
        if ((threadIdx.x & 63) == 0) red[threadIdx.x >> 6] = acc;
        __syncthreads();
        if (threadIdx.x == 0) {
            float v = red[0] + red[1] + red[2] + red[3];
            x0b[b * Cc + c] = f2b(v);
        }
        return;
    }
    int g = blockIdx.x * 256 + threadIdx.x;
    int b = g >> 14, r = g & 16383;
    const u16* p1 = pxc + ((size_t)b * SPLIT) * 16384 + r;
    const u16* p2 = pps + ((size_t)b * SPLIT) * 16384 + r;
    float a1 = 0.f, a2 = 0.f;
    #pragma unroll
    for (int s2 = 0; s2 < SPLIT; s2++) {
        a1 += b2f(p1[(size_t)s2 * 16384]);
        a2 += b2f(p2[(size_t)s2 * 16384]);
    }
    xcT[g] = f2b(a1); psT[g] = f2b(a2);
}

// MFMA mix v2: blocks 0..127 = per-mode mixing, 128 = f0, 129..136 = conv_fill.
__global__ __launch_bounds__(256) void mix_mfma(
    const u16* __restrict__ xcT, const u16* __restrict__ psT,
    const u16* __restrict__ wcT, const u16* __restrict__ wsT,
    const u16* __restrict__ w0T, const u16* __restrict__ x0b,
    const u16* __restrict__ conv_w,
    u16* __restrict__ Ablk, float* __restrict__ f0p, int l) {
    int kb = blockIdx.x;
    int w = threadIdx.x >> 6, lane = threadIdx.x & 63;
    int lo = lane & 15, q = lane >> 4;
    if (kb >= 129) {
        int bcv = kb - 129;
        int o = threadIdx.x >> 1, half = threadIdx.x & 1;
        #pragma unroll
        for (int ks2 = 0; ks2 < 4; ks2++) {
            const u16* src = conv_w + ((size_t)(l * 128 + o)) * 128 + ks2 * 32 + half * 16;
            u16* dst = Ablk + (((size_t)(bcv * 12 + 8 + ks2)) * 128 + o) * 32 + half * 16;
            *(uint4*)dst = *(const uint4*)src;
            *(uint4*)(dst + 8) = *(const uint4*)(src + 8);
        }
        return;
    }
    if (kb == 128) {
        const u16* Arow = x0b + (lo & 7) * 128 + q * 8;
        f4 acc[2] = {};
        #pragma unroll
        for (int step = 0; step < 4; step++) {
            bf8 av = *(const bf8*)(Arow + step * 32);
            #pragma unroll
            for (int nt = 0; nt < 2; nt++) {
                int o = w * 32 + nt * 16 + lo;
                bf8 bv = *(const bf8*)(w0T + ((size_t)(l * 128 + o)) * 128 + q * 8 + step * 32);
                acc[nt] = __builtin_amdgcn_mfma_f32_16x16x32_bf16(av, bv, acc[nt], 0, 0, 0);
            }
        }
        if (q < 2) {
            #pragma unroll
            for (int nt = 0; nt < 2; nt++)
                #pragma unroll
                for (int r = 0; r < 4; r++) {
                    int bb = q * 4 + r, o = w * 32 + nt * 16 + lo;
                    f0p[bb * 128 + o] = acc[nt][r];
                }
        }
        return;
    }
    int k = kb;
    const u16* Arow = (lo < 8)
        ? xcT + ((size_t)(lo * 128 + k)) * 128 + q * 8
        : psT + ((size_t)((lo - 8) * 128 + k)) * 128 + q * 8;
    const u16* wc_l = wcT + ((size_t)(l * 128 + k)) * (128 * 128);
    const u16* ws_l = wsT + ((size_t)(l * 128 + k)) * (128 * 128);
    f4 accC[2] = {}, accS[2] = {};
    #pragma unroll
    for (int step = 0; step < 4; step++) {
        bf8 av = *(const bf8*)(Arow + step * 32);
        #pragma unroll
        for (int nt = 0; nt < 2; nt++) {
            int o = w * 32 + nt * 16 + lo;
            bf8 bc = *(const bf8*)(wc_l + (size_t)o * 128 + q * 8 + step * 32);
            bf8 bs = *(const bf8*)(ws_l + (size_t)o * 128 + q * 8 + step * 32);
            accC[nt] = __builtin_amdgcn_mfma_f32_16x16x32_bf16(av, bc, accC[nt], 0, 0, 0);
            accS[nt] = __builtin_amdgcn_mfma_f32_16x16x32_bf16(av, bs, accS[nt], 0, 0, 0);
        }
    }
    #pragma unroll
    for (int nt = 0; nt < 2; nt++)
        #pragma unroll
        for (int r = 0; r < 4; r++) {
            float uc = accC[nt][r], us = accS[nt][r];
            float ucp = __shfl_xor(uc, 32, 64);
            float usp = __shfl_xor(us, 32, 64);
            if (q < 2) {
                int bb = q * 4 + r, o = w * 32 + nt * 16 + lo;
                float fcv = uc + usp;
                float fsv = us - ucp;
                Ablk[(((size_t)(bb * 12 + (k >> 5))) * 128 + o) * 32 + (k & 31)] = f2b(2.f * fcv);
                Ablk[(((size_t)(bb * 12 + 4 + (k >> 5))) * 128 + o) * 32 + (k & 31)] = f2b(-2.f * fsv);
            }
        }
}

// Ablk1[ks(4)][o(128)][32] = fc1_w^T
__global__ __launch_bounds__(256) void buildA1_blk(
    const u16* __restrict__ fc1_w, u16* __restrict__ Ablk1) {
    int ks = blockIdx.x, t = threadIdx.x;
    int o = t >> 1, half = t & 1;
    u16 ov[16] __attribute__((aligned(16)));
    #pragma unroll
    for (int j = 0; j < 16; j++) {
        int kk = ks * 32 + half * 16 + j;
        ov[j] = fc1_w[kk * 128 + o];
    }
    u16* dst = Ablk1 + ((size_t)ks * 128 + o) * 32 + half * 16;
    *(uint4*)dst = *(const uint4*)ov;
    *(uint4*)(dst + 8) = *(const uint4*)(ov + 8);
}

// MFMA combine v9 (best-known): global_load_lds staging for A and B, counted
// vmcnt(4) + raw s_barrier; linear LDS dest + inverse-swizzled global source +
// swizzled ds_read (chunk pos ^= (row>>1)&3).
// EPI 0: gelu, write h (in place) + hw_cn. EPI 1: no gelu, h only. EPI 2: fc1+fc2 -> psum.
template <int EPI, int NKS>
__global__ __launch_bounds__(256) void combine_mfma(
    const u16* __restrict__ Ablk, long astr,
    const u16* __restrict__ bigB, u16* __restrict__ h,
    u16* __restrict__ hw_cn,
    const float* __restrict__ f0p, const u16* __restrict__ bias,
    const u16* __restrict__ mask, const u16* __restrict__ wn,
    const u16* __restrict__ fc2w, float* __restrict__ psum) {
    __shared__ u16 lds[17408];   // staging: 2 buf x (A 4096 + B 4096) u16 = 32KB; epilogue union 34KB
    int b = blockIdx.y;
    int nb = blockIdx.x * 128;
    int t = threadIdx.x;
    int w = t >> 6, lane = t & 63;
    int lo = lane & 15, q = lane >> 4;
    int wo = (w & 1) * 64, wn2 = (w >> 1) * 64;

    const u16* Ab = Ablk + (size_t)b * astr;

    // fragment read offsets (u16 units, loop-invariant): row*32 + swizzled-chunk*8
    int aoffs[4], boffs[4];
    #pragma unroll
    for (int ot = 0; ot < 4; ot++) {
        int o = wo + ot * 16 + lo;
        aoffs[ot] = o * 32 + (q ^ ((o >> 1) & 3)) * 8;
    }
    #pragma unroll
    for (int nt = 0; nt < 4; nt++) {
        int r = wn2 + nt * 16 + lo;
        boffs[nt] = r * 32 + (q ^ ((r >> 1) & 3)) * 8;
    }

    // stage K-step ksn into buffer pb: 4 gload_lds per wave (2 A + 2 B).
    auto STAGE = [&](int ksn, int pb) {
        #pragma unroll
        for (int j = 0; j < 2; j++) {
            int c = j * 256 + w * 64 + lane;
            int row = c >> 2, p = c & 3;
            int sp = p ^ ((row >> 1) & 3);
            const u16* abase = lds + pb * 8192 + (j * 256 + w * 64) * 8;   // wave-uniform
            gload16(Ab + (size_t)ksn * 4096 + row * 32 + sp * 8, abase);
            const u16* bsrc;
            size_t nrow = (size_t)b * Nn + nb + row;
            if (EPI == 2)       bsrc = h + nrow * 128 + ksn * 32;
            else if (ksn < 8)   bsrc = bigB + nrow * 256 + ksn * 32;
            else                bsrc = h + nrow * 128 + (ksn - 8) * 32;
            const u16* bbase = lds + pb * 8192 + 4096 + (j * 256 + w * 64) * 8;
            gload16(bsrc + sp * 8, bbase);
        }
        __builtin_amdgcn_sched_barrier(0);
    };

    STAGE(0, 0);
    if (NKS > 1) STAGE(1, 1);

    f4 acc[4][4] = {};
    #pragma unroll
    for (int ks = 0; ks < NKS; ks++) {
        // wait for stage ks (leave stage ks+1's 4 loads in flight), then sync
        if (ks + 1 < NKS) asm volatile("s_waitcnt vmcnt(4)" ::: "memory");
        else              asm volatile("s_waitcnt vmcnt(0)" ::: "memory");
        __builtin_amdgcn_sched_barrier(0);
        __builtin_amdgcn_s_barrier();
        __builtin_amdgcn_sched_barrier(0);

        int pb = ks & 1;
        const u16* base = lds + pb * 8192;
        bf8 avf[4], bvf[4];
        #pragma unroll
        for (int ot = 0; ot < 4; ot++) avf[ot] = *(const bf8*)(base + aoffs[ot]);
        #pragma unroll
        for (int nt = 0; nt < 4; nt++) bvf[nt] = *(const bf8*)(base + 4096 + boffs[nt]);
        #pragma unroll
        for (int ot = 0; ot < 4; ot++)
            #pragma unroll
            for (int nt = 0; nt < 4; nt++)
                acc[ot][nt] = __builtin_amdgcn_mfma_f32_16x16x32_bf16(avf[ot], bvf[nt], acc[ot][nt], 0, 0, 0);

        // all my ds_reads of buf[pb] complete before signaling reuse barrier
        asm volatile("s_waitcnt lgkmcnt(0)" ::: "memory");
        __builtin_amdgcn_sched_barrier(0);
        __builtin_amdgcn_s_barrier();
        __builtin_amdgcn_sched_barrier(0);
        if (ks + 2 < NKS) STAGE(ks + 2, pb);
    }

    if (EPI == 2) {
        #pragma unroll
        for (int nt = 0; nt < 4; nt++) {
            int n = nb + wn2 + nt * 16 + lo;
            float s = 0.f;
            #pragma unroll
            for (int ot = 0; ot < 4; ot++)
                #pragma unroll
                for (int r = 0; r < 4; r++) {
                    int o = wo + ot * 16 + q * 4 + r;
                    float v = acc[ot][nt][r] + b2f(bias[o]);
                    v = gelu_f(v);
                    s += b2f(fc2w[o]) * v;
                }
            s += __shfl_xor(s, 16, 64);
            s += __shfl_xor(s, 32, 64);
            if (q == 0)
                psum[(size_t)(w & 1) * (Bb * Nn) + (size_t)b * Nn + n] = s;
        }
    } else {
        u16* tile = lds + w * 4352;   // 64n x 68 pitch
        #pragma unroll
        for (int nt = 0; nt < 4; nt++) {
            int n = nb + wn2 + nt * 16 + lo;
            float mv = b2f(mask[(size_t)b * Nn + n]);
            #pragma unroll
            for (int ot = 0; ot < 4; ot++) {
                u16 hv[4] __attribute__((aligned(8)));
                #pragma unroll
                for (int r = 0; r < 4; r++) {
                    int o = wo + ot * 16 + q * 4 + r;
                    float v = acc[ot][nt][r] + b2f(bias[o]) + f0p[b * Cc + o] * mv;
                    if (EPI == 0) v = gelu_f(v);
                    hv[r] = f2b(v);
                }
                *(uint2*)&tile[(nt * 16 + lo) * 68 + ot * 16 + q * 4] = *(const uint2*)hv;
            }
        }
        __syncthreads();
        #pragma unroll
        for (int it = 0; it < 8; it++) {
            int row = it * 8 + (lane >> 3), seg = lane & 7;
            uint4 v4 = *(const uint4*)&tile[row * 68 + seg * 8];
            *(uint4*)&h[((size_t)b * Nn + nb + wn2 + row) * 128 + wo + seg * 8] = v4;
        }
        if (EPI == 0) {
            // emit hw_cn[c][n] from the wave's 64n x 64o tile (c = wo+lane)
            int c = wo + lane;
            const u16* wnp = wn + (size_t)b * Nn + nb + wn2;
            u16* dstp = hw_cn + ((size_t)(b * Cc) + c) * Nn + nb + wn2;
            #pragma unroll
            for (int i = 0; i < 8; i++) {
                u16 hv8[8] __attribute__((aligned(16)));
                #pragma unroll
                for (int j2 = 0; j2 < 8; j2++) {
                    int nl2 = i * 8 + j2;
                    hv8[j2] = f2b(b2f(tile[nl2 * 68 + lane]) * b2f(wnp[nl2]));
                }
                *(uint4*)(dstp + i * 8) = *(const uint4*)hv8;
            }
        }
    }
}

// out = (psum0 + psum1 + fc2_b) * mask, dtype per flag
__global__ __launch_bounds__(256) void fc2_final(
    const float* __restrict__ psum, const u16* __restrict__ fc2b,
    const u16* __restrict__ mask, void* __restrict__ out, const int* __restrict__ flag) {
    int g = blockIdx.x * 256 + threadIdx.x;   // < Bb*Nn
    float s = psum[g] + psum[(size_t)Bb * Nn + g] + b2f(fc2b[0]);
    s *= b2f(mask[g]);
    if (*flag) ((u16*)out)[g] = f2b(s);
    else       ((float*)out)[g] = s;
}

extern "C" void kernel_launch(void* const* d_in, const int* in_sizes, int n_in,
                              void* d_out, int out_size, void* d_ws, size_t ws_size,
                              hipStream_t stream) {
    char* p = (char*)d_ws;
    auto alloc = [&](size_t bytes) { void* r = (void*)p; p += (bytes + 255) & ~(size_t)255; return r; };

    int* flag = (int*)alloc(256);

    SegTable tab;
    u16* nin[16];
    for (int i = 0; i < 16; i++) {
        tab.src[i] = d_in[i];
        if (i == 7 || i == 8) {
            nin[i] = (u16*)flag;
            tab.dst[i] = nin[i];
            tab.count[i] = 0;
        } else {
            int cnt = in_sizes[i];
            nin[i] = (u16*)alloc((size_t)cnt * 2);
            tab.dst[i] = nin[i];
            tab.count[i] = cnt;
        }
    }
    const u16* x      = nin[0];
    const u16* nodes  = nin[1];
    const u16* mask   = nin[2];
    const u16* wn     = nin[3];
    const u16* modes  = nin[4];
    const u16* fc0_w  = nin[5];
    const u16* fc0_b  = nin[6];
    const u16* w0n    = nin[9];
    const u16* conv_w = nin[10];
    const u16* conv_b = nin[11];
    const u16* fc1_w  = nin[12];
    const u16* fc1_b  = nin[13];
    const u16* fc2_w  = nin[14];
    const u16* fc2_b  = nin[15];

    u16* bigB   = (u16*)alloc((size_t)Bb * Nn * 256 * 2);        // 67.1 MB
    u16* hA     = (u16*)alloc((size_t)Bb * Nn * 128 * 2);        // 33.6 MB
    u16* hw_cn  = (u16*)alloc((size_t)Bb * Cc * Nn * 2);         // 33.6 MB
    u16* pxc    = (u16*)alloc((size_t)Bb * SPLIT * Cc * Kk * 2); // 8.4 MB
    u16* pps    = (u16*)alloc((size_t)Bb * SPLIT * Cc * Kk * 2); // 8.4 MB
    u16* wcT    = (u16*)alloc((size_t)Ll * Kk * Cc * Cc * 2);    // 16.8 MB
    u16* wsT    = (u16*)alloc((size_t)Ll * Kk * Cc * Cc * 2);    // 16.8 MB
    u16* w0T    = (u16*)alloc((size_t)Ll * Cc * Cc * 2);
    u16* xcT    = (u16*)alloc((size_t)Bb * Kk * Cc * 2);
    u16* psT    = (u16*)alloc((size_t)Bb * Kk * Cc * 2);
    u16* x0b    = (u16*)alloc((size_t)Bb * Cc * 2);
    float* f0f  = (float*)alloc((size_t)Bb * Cc * 4);
    u16* Ablk   = (u16*)alloc((size_t)Bb * 12 * 128 * 32 * 2);
    u16* Ablk1  = (u16*)alloc((size_t)4 * 128 * 32 * 2);
    float* psum = (float*)alloc((size_t)2 * Bb * Nn * 4);        // 1.0 MB
    // total ws ~= 190 MB

    const long ASTR = 12L * 128 * 32;

    detect_kernel<<<1, 64, 0, stream>>>((const unsigned int*)d_in[2], flag);
    convert_kernel<<<512, 256, 0, stream>>>(tab, flag);

    transpose_w<<<dim3(129, Ll), 256, 0, stream>>>(d_in[7], d_in[8], w0n, wcT, wsT, w0T, flag);
    prep_nk<<<dim3(Nn / 64, Bb), 256, 0, stream>>>(
        nodes, modes, mask, bigB, x, fc0_w, fc0_b, wn, hA, hw_cn);

    for (int l = 0; l < Ll; l++) {
        proj_mfma<<<dim3(SPLIT, Bb), 512, 0, stream>>>(hw_cn, nodes, modes, mask, pxc, pps);
        reduce_kernel<<<dim3(512 + Bb * Cc), 256, 0, stream>>>(pxc, pps, xcT, psT, hw_cn, mask, x0b);
        mix_mfma<<<dim3(137), 256, 0, stream>>>(xcT, psT, wcT, wsT, w0T, x0b, conv_w, Ablk, f0f, l);
        if (l < Ll - 1) {
            combine_mfma<0, 12><<<dim3(Nn / 128, Bb), 256, 0, stream>>>(
                Ablk, ASTR, bigB, hA, hw_cn, f0f, conv_b + l * Cc, mask, wn, fc2_w, psum);
        } else {
            combine_mfma<1, 12><<<dim3(Nn / 128, Bb), 256, 0, stream>>>(
                Ablk, ASTR, bigB, hA, hw_cn, f0f, conv_b + l * Cc, mask, wn, fc2_w, psum);
        }
    }

    buildA1_blk<<<dim3(4), 256, 0, stream>>>(fc1_w, Ablk1);
    combine_mfma<2, 4><<<dim3(Nn / 128, Bb), 256, 0, stream>>>(
        Ablk1, 0L, bigB, hA, hw_cn, f0f, fc1_b, mask, wn, fc2_w, psum);
    fc2_final<<<dim3((Bb * Nn) / 256), 256, 0, stream>>>(psum, fc2_b, mask, d_out, flag);
}

// Round 12
// 601.493 us; speedup vs baseline: 1.0822x; 1.0822x over previous
//
#include <hip/hip_runtime.h>

using u16 = unsigned short;
typedef short bf8 __attribute__((ext_vector_type(8)));
typedef float f4 __attribute__((ext_vector_type(4)));

constexpr int Bb = 8;
constexpr int Nn = 16384;
constexpr int Kk = 128;
constexpr int Cc = 128;
constexpr int Ll = 4;
constexpr int SPLIT = 32;

__device__ __forceinline__ float b2f(u16 u) {
    union { unsigned int i; float f; } v; v.i = ((unsigned int)u) << 16; return v.f;
}
__device__ __forceinline__ u16 f2b(float f) {
    union { float f; unsigned int i; } v; v.f = f;
    unsigned int i = v.i;
    return (u16)((i + 0x7fffu + ((i >> 16) & 1u)) >> 16);
}
__device__ __forceinline__ float gelu_f(float x) {
    return 0.5f * x * (1.0f + erff(x * 0.70710678118654752f));
}

__device__ __forceinline__ void gload16(const void* g, const u16* l) {
    __builtin_amdgcn_global_load_lds(
        (const __attribute__((address_space(1))) void*)g,
        (__attribute__((address_space(3))) void*)(u16*)l, 16, 0, 0);
}

// ---- dtype detection + input normalization ----
__global__ void detect_kernel(const unsigned int* __restrict__ maskw, int* __restrict__ flag) {
    if (threadIdx.x == 0 && blockIdx.x == 0)
        *flag = ((maskw[0] & 0xFFFFu) != 0u) ? 1 : 0;   // 1 = inputs are bf16
}

struct SegTable {
    const void* src[16];
    u16* dst[16];
    int count[16];
};

__global__ __launch_bounds__(256) void convert_kernel(SegTable t, const int* __restrict__ flag) {
    const int f = *flag;
    const int stride = gridDim.x * 256;
    for (int seg = 0; seg < 16; ++seg) {
        const int cnt = t.count[seg];
        const void* s = t.src[seg];
        u16* d = t.dst[seg];
        for (int i = blockIdx.x * 256 + threadIdx.x; i < cnt; i += stride) {
            d[i] = f ? ((const u16*)s)[i] : f2b(((const float*)s)[i]);
        }
    }
}

// prep_nk: fused bases_nk (bigB) + fc0_nk (hA, hw_cn) — identical grids,
// independent inputs/outputs; bodies verbatim. Saves one launch boundary.
__global__ __launch_bounds__(256) void prep_nk(
    const u16* __restrict__ nodes, const u16* __restrict__ modes,
    const u16* __restrict__ mask, u16* __restrict__ bigB,
    const u16* __restrict__ x, const u16* __restrict__ fc0_w,
    const u16* __restrict__ fc0_b, const u16* __restrict__ wn,
    u16* __restrict__ hA, u16* __restrict__ hw_cn) {
    int t = threadIdx.x;
    int nl = t >> 2, kp = t & 3;
    int n = blockIdx.x * 64 + nl, b = blockIdx.y;
    // ---- bases part ----
    {
        float nx = b2f(nodes[((size_t)(b * Nn + n)) * 2]);
        float ny = b2f(nodes[((size_t)(b * Nn + n)) * 2 + 1]);
        float mk = b2f(mask[b * Nn + n]);
        u16 cb[32] __attribute__((aligned(16)));
        u16 sb[32] __attribute__((aligned(16)));
        #pragma unroll
        for (int j = 0; j < 32; j++) {
            int k = kp * 32 + j;
            float m0 = b2f(modes[k * 2]), m1 = b2f(modes[k * 2 + 1]);
            float tt = nx * m0 + ny * m1;
            float sv, cv;
            __sincosf(tt, &sv, &cv);
            cb[j] = f2b(cv * mk);
            sb[j] = f2b(sv * mk);
        }
        u16* row = bigB + ((size_t)b * Nn + n) * 256;
        #pragma unroll
        for (int i = 0; i < 4; i++) {
            *(uint4*)(row + kp * 32 + i * 8)       = *(const uint4*)(cb + i * 8);
            *(uint4*)(row + 128 + kp * 32 + i * 8) = *(const uint4*)(sb + i * 8);
        }
    }
    // ---- fc0 part ----
    {
        const u16* xp = x + ((size_t)(b * Nn + n)) * 3;
        float x0v = b2f(xp[0]), x1v = b2f(xp[1]), x2v = b2f(xp[2]);
        float wv = b2f(wn[b * Nn + n]);
        u16 hb[32] __attribute__((aligned(16)));
        #pragma unroll
        for (int j = 0; j < 32; j++) {
            int c = kp * 32 + j;
            float acc = b2f(fc0_b[c]);
            acc += x0v * b2f(fc0_w[0 * Cc + c]);
            acc += x1v * b2f(fc0_w[1 * Cc + c]);
            acc += x2v * b2f(fc0_w[2 * Cc + c]);
            hb[j] = f2b(acc);
            hw_cn[((size_t)(b * Cc + c)) * Nn + n] = f2b(acc * wv);
        }
        u16* row = hA + ((size_t)b * Nn + n) * 128 + kp * 32;
        #pragma unroll
        for (int i = 0; i < 4; i++) *(uint4*)(row + i * 8) = *(const uint4*)(hb + i * 8);
    }
}

// one-shot all layers: wcT/wsT[l][k][o][i] bf16 from raw [l][i][o][k]; w0T[l][o][i]
__global__ __launch_bounds__(256) void transpose_w(
    const void* __restrict__ wcraw, const void* __restrict__ wsraw,
    const u16* __restrict__ w0n,
    u16* __restrict__ wcT, u16* __restrict__ wsT, u16* __restrict__ w0T,
    const int* __restrict__ flag) {
    __shared__ u16 tile[128][136];
    int o = blockIdx.x, l = blockIdx.y, t = threadIdx.x;
    const int f = *flag;
    if (o == 128) {
        int i = t >> 1, oh = (t & 1) * 64;
        #pragma unroll
        for (int j = 0; j < 64; j += 8)
            *(uint4*)&tile[i][oh + j] = *(const uint4*)(w0n + ((size_t)(l * 128 + i)) * 128 + oh + j);
        __syncthreads();
        int o2 = t >> 1, ih = (t & 1) * 64;
        u16 buf[64] __attribute__((aligned(16)));
        #pragma unroll
        for (int j = 0; j < 64; j++) buf[j] = tile[ih + j][o2];
        #pragma unroll
        for (int j = 0; j < 64; j += 8)
            *(uint4*)(w0T + ((size_t)(l * 128 + o2)) * 128 + ih + j) = *(const uint4*)(buf + j);
        return;
    }
    for (int wsel = 0; wsel < 2; wsel++) {
        if (wsel) __syncthreads();
        const void* raw = wsel ? wsraw : wcraw;
        u16* dst = wsel ? wsT : wcT;
        int i = t >> 1, kh = (t & 1) * 64;
        size_t base = (((size_t)(l * 128 + i)) * 128 + o) * 128 + kh;
        if (f) {
            #pragma unroll
            for (int j = 0; j < 64; j += 8)
                *(uint4*)&tile[i][kh + j] = *(const uint4*)((const u16*)raw + base + j);
        } else {
            #pragma unroll
            for (int j = 0; j < 64; j += 4) {
                float4 v = *(const float4*)((const float*)raw + base + j);
                u16 o4[4] __attribute__((aligned(8))) = { f2b(v.x), f2b(v.y), f2b(v.z), f2b(v.w) };
                *(unsigned long long*)&tile[i][kh + j] = *(const unsigned long long*)o4;
            }
        }
        __syncthreads();
        int k = t >> 1, ih = (t & 1) * 64;
        u16 buf[64] __attribute__((aligned(16)));
        #pragma unroll
        for (int j = 0; j < 64; j++) buf[j] = tile[ih + j][k];
        #pragma unroll
        for (int j = 0; j < 64; j += 8)
            *(uint4*)(dst + (((size_t)(l * 128 + k)) * 128 + o) * 128 + ih + j) = *(const uint4*)(buf + j);
    }
}

// MFMA projection v6 (restored, proven in the 607us config): grid (32, 2, 8) =
// 512 blocks. Block covers c-half (ch = blockIdx.y) x ALL 128 modes x 512 n.
// 4 waves; each wave handles 2 k-tiles sharing one A-load (4 c-tile streams).
__global__ __launch_bounds__(256) void proj_mfma(
    const u16* __restrict__ hw, const u16* __restrict__ nodes,
    const u16* __restrict__ modes, const u16* __restrict__ mask,
    u16* __restrict__ pxc, u16* __restrict__ pps) {
    int s = blockIdx.x, ch = blockIdx.y, b = blockIdx.z;
    int w = threadIdx.x >> 6, lane = threadIdx.x & 63;
    int lo = lane & 15, q = lane >> 4;
    int n0 = s * 512;
    int km0 = w * 16 + lo;          // k-tile 0 mode
    int km1 = 64 + w * 16 + lo;     // k-tile 1 mode
    float m00 = b2f(modes[km0 * 2]), m01 = b2f(modes[km0 * 2 + 1]);
    float m10 = b2f(modes[km1 * 2]), m11 = b2f(modes[km1 * 2 + 1]);
    const u16* ap[4];
    #pragma unroll
    for (int ct = 0; ct < 4; ct++)
        ap[ct] = hw + ((size_t)(b * Cc) + ch * 64 + ct * 16 + lo) * Nn + n0 + q * 8;
    const u16* np = nodes + ((size_t)(b * Nn) + n0 + q * 8) * 2;
    const u16* mp = mask + (size_t)b * Nn + n0 + q * 8;
    f4 aC[2][4] = {}, aS[2][4] = {};
    for (int js = 0; js < 16; js++) {
        int off = js * 32;
        uint4 nq0 = *(const uint4*)(np + off * 2);
        uint4 nq1 = *(const uint4*)(np + off * 2 + 8);
        uint4 mq  = *(const uint4*)(mp + off);
        float xs[8], ys[8], mk[8];
        xs[0] = b2f(nq0.x & 0xffffu); ys[0] = b2f(nq0.x >> 16);
        xs[1] = b2f(nq0.y & 0xffffu); ys[1] = b2f(nq0.y >> 16);
        xs[2] = b2f(nq0.z & 0xffffu); ys[2] = b2f(nq0.z >> 16);
        xs[3] = b2f(nq0.w & 0xffffu); ys[3] = b2f(nq0.w >> 16);
        xs[4] = b2f(nq1.x & 0xffffu); ys[4] = b2f(nq1.x >> 16);
        xs[5] = b2f(nq1.y & 0xffffu); ys[5] = b2f(nq1.y >> 16);
        xs[6] = b2f(nq1.z & 0xffffu); ys[6] = b2f(nq1.z >> 16);
        xs[7] = b2f(nq1.w & 0xffffu); ys[7] = b2f(nq1.w >> 16);
        mk[0] = b2f(mq.x & 0xffffu);  mk[1] = b2f(mq.x >> 16);
        mk[2] = b2f(mq.y & 0xffffu);  mk[3] = b2f(mq.y >> 16);
        mk[4] = b2f(mq.z & 0xffffu);  mk[5] = b2f(mq.z >> 16);
        mk[6] = b2f(mq.w & 0xffffu);  mk[7] = b2f(mq.w >> 16);
        u16 cf0[8] __attribute__((aligned(16)));
        u16 sf0[8] __attribute__((aligned(16)));
        u16 cf1[8] __attribute__((aligned(16)));
        u16 sf1[8] __attribute__((aligned(16)));
        #pragma unroll
        for (int j = 0; j < 8; j++) {
            float t0 = xs[j] * m00 + ys[j] * m01;
            float s0, c0;
            __sincosf(t0, &s0, &c0);
            cf0[j] = f2b(c0 * mk[j]);
            sf0[j] = f2b(s0 * mk[j]);
            float t1 = xs[j] * m10 + ys[j] * m11;
            float s1, c1;
            __sincosf(t1, &s1, &c1);
            cf1[j] = f2b(c1 * mk[j]);
            sf1[j] = f2b(s1 * mk[j]);
        }
        bf8 cv0 = *(const bf8*)cf0;
        bf8 sv0 = *(const bf8*)sf0;
        bf8 cv1 = *(const bf8*)cf1;
        bf8 sv1 = *(const bf8*)sf1;
        #pragma unroll
        for (int ct = 0; ct < 4; ct++) {
            bf8 av = *(const bf8*)(ap[ct] + off);
            aC[0][ct] = __builtin_amdgcn_mfma_f32_16x16x32_bf16(av, cv0, aC[0][ct], 0, 0, 0);
            aS[0][ct] = __builtin_amdgcn_mfma_f32_16x16x32_bf16(av, sv0, aS[0][ct], 0, 0, 0);
            aC[1][ct] = __builtin_amdgcn_mfma_f32_16x16x32_bf16(av, cv1, aC[1][ct], 0, 0, 0);
            aS[1][ct] = __builtin_amdgcn_mfma_f32_16x16x32_bf16(av, sv1, aS[1][ct], 0, 0, 0);
        }
    }
    #pragma unroll
    for (int kt = 0; kt < 2; kt++) {
        int kmode = kt * 64 + w * 16 + lo;
        size_t base = ((size_t)(b * SPLIT + s)) * 16384 + (size_t)kmode * 128;
        #pragma unroll
        for (int ct = 0; ct < 4; ct++) {
            int c0 = ch * 64 + ct * 16 + q * 4;
            u16 pc[4] __attribute__((aligned(8)));
            u16 pssv[4] __attribute__((aligned(8)));
            #pragma unroll
            for (int r = 0; r < 4; r++) { pc[r] = f2b(aC[kt][ct][r]); pssv[r] = f2b(aS[kt][ct][r]); }
            *(uint2*)&pxc[base + c0] = *(const uint2*)pc;
            *(uint2*)&pps[base + c0] = *(const uint2*)pssv;
        }
    }
}

// reduce v2: blocks 0..511 = bf16 partial sum over s (unchanged math);
// blocks 512..1535 = the old x0_kernel verbatim (x0[b,c] = sum_n hw*mask).
__global__ __launch_bounds__(256) void reduce_kernel(
    const u16* __restrict__ pxc, const u16* __restrict__ pps,
    u16* __restrict__ xcT, u16* __restrict__ psT,
    const u16* __restrict__ hw, const u16* __restrict__ mask,
    u16* __restrict__ x0b) {
    __shared__ float red[4];
    if (blockIdx.x >= 512) {
        int xb = blockIdx.x - 512;
        int c = xb & 127, b = xb >> 7;
        const u16* row = hw + ((size_t)(b * Cc + c)) * Nn;
        const u16* mrow = mask + (size_t)b * Nn;
        float acc = 0.f;
        for (int n = threadIdx.x; n < Nn; n += 256) acc += b2f(row[n]) * b2f(mrow[n]);
        for (int off = 32; off; off >>= 1) acc += __shfl_down(acc, off, 64);
        if ((threadIdx.x & 63) == 0) red[threadIdx.x >> 6] = acc;
        __syncthreads();
        if (threadIdx.x == 0) {
            float v = red[0] + red[1] + red[2] + red[3];
            x0b[b * Cc + c] = f2b(v);
        }
        return;
    }
    int g = blockIdx.x * 256 + threadIdx.x;
    int b = g >> 14, r = g & 16383;
    const u16* p1 = pxc + ((size_t)b * SPLIT) * 16384 + r;
    const u16* p2 = pps + ((size_t)b * SPLIT) * 16384 + r;
    float a1 = 0.f, a2 = 0.f;
    #pragma unroll
    for (int s2 = 0; s2 < SPLIT; s2++) {
        a1 += b2f(p1[(size_t)s2 * 16384]);
        a2 += b2f(p2[(size_t)s2 * 16384]);
    }
    xcT[g] = f2b(a1); psT[g] = f2b(a2);
}

// MFMA mix v2: blocks 0..127 = per-mode mixing, 128 = f0, 129..136 = conv_fill.
__global__ __launch_bounds__(256) void mix_mfma(
    const u16* __restrict__ xcT, const u16* __restrict__ psT,
    const u16* __restrict__ wcT, const u16* __restrict__ wsT,
    const u16* __restrict__ w0T, const u16* __restrict__ x0b,
    const u16* __restrict__ conv_w,
    u16* __restrict__ Ablk, float* __restrict__ f0p, int l) {
    int kb = blockIdx.x;
    int w = threadIdx.x >> 6, lane = threadIdx.x & 63;
    int lo = lane & 15, q = lane >> 4;
    if (kb >= 129) {
        int bcv = kb - 129;
        int o = threadIdx.x >> 1, half = threadIdx.x & 1;
        #pragma unroll
        for (int ks2 = 0; ks2 < 4; ks2++) {
            const u16* src = conv_w + ((size_t)(l * 128 + o)) * 128 + ks2 * 32 + half * 16;
            u16* dst = Ablk + (((size_t)(bcv * 12 + 8 + ks2)) * 128 + o) * 32 + half * 16;
            *(uint4*)dst = *(const uint4*)src;
            *(uint4*)(dst + 8) = *(const uint4*)(src + 8);
        }
        return;
    }
    if (kb == 128) {
        const u16* Arow = x0b + (lo & 7) * 128 + q * 8;
        f4 acc[2] = {};
        #pragma unroll
        for (int step = 0; step < 4; step++) {
            bf8 av = *(const bf8*)(Arow + step * 32);
            #pragma unroll
            for (int nt = 0; nt < 2; nt++) {
                int o = w * 32 + nt * 16 + lo;
                bf8 bv = *(const bf8*)(w0T + ((size_t)(l * 128 + o)) * 128 + q * 8 + step * 32);
                acc[nt] = __builtin_amdgcn_mfma_f32_16x16x32_bf16(av, bv, acc[nt], 0, 0, 0);
            }
        }
        if (q < 2) {
            #pragma unroll
            for (int nt = 0; nt < 2; nt++)
                #pragma unroll
                for (int r = 0; r < 4; r++) {
                    int bb = q * 4 + r, o = w * 32 + nt * 16 + lo;
                    f0p[bb * 128 + o] = acc[nt][r];
                }
        }
        return;
    }
    int k = kb;
    const u16* Arow = (lo < 8)
        ? xcT + ((size_t)(lo * 128 + k)) * 128 + q * 8
        : psT + ((size_t)((lo - 8) * 128 + k)) * 128 + q * 8;
    const u16* wc_l = wcT + ((size_t)(l * 128 + k)) * (128 * 128);
    const u16* ws_l = wsT + ((size_t)(l * 128 + k)) * (128 * 128);
    f4 accC[2] = {}, accS[2] = {};
    #pragma unroll
    for (int step = 0; step < 4; step++) {
        bf8 av = *(const bf8*)(Arow + step * 32);
        #pragma unroll
        for (int nt = 0; nt < 2; nt++) {
            int o = w * 32 + nt * 16 + lo;
            bf8 bc = *(const bf8*)(wc_l + (size_t)o * 128 + q * 8 + step * 32);
            bf8 bs = *(const bf8*)(ws_l + (size_t)o * 128 + q * 8 + step * 32);
            accC[nt] = __builtin_amdgcn_mfma_f32_16x16x32_bf16(av, bc, accC[nt], 0, 0, 0);
            accS[nt] = __builtin_amdgcn_mfma_f32_16x16x32_bf16(av, bs, accS[nt], 0, 0, 0);
        }
    }
    #pragma unroll
    for (int nt = 0; nt < 2; nt++)
        #pragma unroll
        for (int r = 0; r < 4; r++) {
            float uc = accC[nt][r], us = accS[nt][r];
            float ucp = __shfl_xor(uc, 32, 64);
            float usp = __shfl_xor(us, 32, 64);
            if (q < 2) {
                int bb = q * 4 + r, o = w * 32 + nt * 16 + lo;
                float fcv = uc + usp;
                float fsv = us - ucp;
                Ablk[(((size_t)(bb * 12 + (k >> 5))) * 128 + o) * 32 + (k & 31)] = f2b(2.f * fcv);
                Ablk[(((size_t)(bb * 12 + 4 + (k >> 5))) * 128 + o) * 32 + (k & 31)] = f2b(-2.f * fsv);
            }
        }
}

// Ablk1[ks(4)][o(128)][32] = fc1_w^T
__global__ __launch_bounds__(256) void buildA1_blk(
    const u16* __restrict__ fc1_w, u16* __restrict__ Ablk1) {
    int ks = blockIdx.x, t = threadIdx.x;
    int o = t >> 1, half = t & 1;
    u16 ov[16] __attribute__((aligned(16)));
    #pragma unroll
    for (int j = 0; j < 16; j++) {
        int kk = ks * 32 + half * 16 + j;
        ov[j] = fc1_w[kk * 128 + o];
    }
    u16* dst = Ablk1 + ((size_t)ks * 128 + o) * 32 + half * 16;
    *(uint4*)dst = *(const uint4*)ov;
    *(uint4*)(dst + 8) = *(const uint4*)(ov + 8);
}

// MFMA combine v9 (best-known): global_load_lds staging for A and B, counted
// vmcnt(4) + raw s_barrier; linear LDS dest + inverse-swizzled global source +
// swizzled ds_read (chunk pos ^= (row>>1)&3).
// EPI 0: gelu, write h (in place) + hw_cn. EPI 1: no gelu, h only. EPI 2: fc1+fc2 -> psum.
template <int EPI, int NKS>
__global__ __launch_bounds__(256) void combine_mfma(
    const u16* __restrict__ Ablk, long astr,
    const u16* __restrict__ bigB, u16* __restrict__ h,
    u16* __restrict__ hw_cn,
    const float* __restrict__ f0p, const u16* __restrict__ bias,
    const u16* __restrict__ mask, const u16* __restrict__ wn,
    const u16* __restrict__ fc2w, float* __restrict__ psum) {
    __shared__ u16 lds[17408];   // staging: 2 buf x (A 4096 + B 4096) u16 = 32KB; epilogue union 34KB
    int b = blockIdx.y;
    int nb = blockIdx.x * 128;
    int t = threadIdx.x;
    int w = t >> 6, lane = t & 63;
    int lo = lane & 15, q = lane >> 4;
    int wo = (w & 1) * 64, wn2 = (w >> 1) * 64;

    const u16* Ab = Ablk + (size_t)b * astr;

    // fragment read offsets (u16 units, loop-invariant): row*32 + swizzled-chunk*8
    int aoffs[4], boffs[4];
    #pragma unroll
    for (int ot = 0; ot < 4; ot++) {
        int o = wo + ot * 16 + lo;
        aoffs[ot] = o * 32 + (q ^ ((o >> 1) & 3)) * 8;
    }
    #pragma unroll
    for (int nt = 0; nt < 4; nt++) {
        int r = wn2 + nt * 16 + lo;
        boffs[nt] = r * 32 + (q ^ ((r >> 1) & 3)) * 8;
    }

    // stage K-step ksn into buffer pb: 4 gload_lds per wave (2 A + 2 B).
    auto STAGE = [&](int ksn, int pb) {
        #pragma unroll
        for (int j = 0; j < 2; j++) {
            int c = j * 256 + w * 64 + lane;
            int row = c >> 2, p = c & 3;
            int sp = p ^ ((row >> 1) & 3);
            const u16* abase = lds + pb * 8192 + (j * 256 + w * 64) * 8;   // wave-uniform
            gload16(Ab + (size_t)ksn * 4096 + row * 32 + sp * 8, abase);
            const u16* bsrc;
            size_t nrow = (size_t)b * Nn + nb + row;
            if (EPI == 2)       bsrc = h + nrow * 128 + ksn * 32;
            else if (ksn < 8)   bsrc = bigB + nrow * 256 + ksn * 32;
            else                bsrc = h + nrow * 128 + (ksn - 8) * 32;
            const u16* bbase = lds + pb * 8192 + 4096 + (j * 256 + w * 64) * 8;
            gload16(bsrc + sp * 8, bbase);
        }
        __builtin_amdgcn_sched_barrier(0);
    };

    STAGE(0, 0);
    if (NKS > 1) STAGE(1, 1);

    f4 acc[4][4] = {};
    #pragma unroll
    for (int ks = 0; ks < NKS; ks++) {
        // wait for stage ks (leave stage ks+1's 4 loads in flight), then sync
        if (ks + 1 < NKS) asm volatile("s_waitcnt vmcnt(4)" ::: "memory");
        else              asm volatile("s_waitcnt vmcnt(0)" ::: "memory");
        __builtin_amdgcn_sched_barrier(0);
        __builtin_amdgcn_s_barrier();
        __builtin_amdgcn_sched_barrier(0);

        int pb = ks & 1;
        const u16* base = lds + pb * 8192;
        bf8 avf[4], bvf[4];
        #pragma unroll
        for (int ot = 0; ot < 4; ot++) avf[ot] = *(const bf8*)(base + aoffs[ot]);
        #pragma unroll
        for (int nt = 0; nt < 4; nt++) bvf[nt] = *(const bf8*)(base + 4096 + boffs[nt]);
        #pragma unroll
        for (int ot = 0; ot < 4; ot++)
            #pragma unroll
            for (int nt = 0; nt < 4; nt++)
                acc[ot][nt] = __builtin_amdgcn_mfma_f32_16x16x32_bf16(avf[ot], bvf[nt], acc[ot][nt], 0, 0, 0);

        // all my ds_reads of buf[pb] complete before signaling reuse barrier
        asm volatile("s_waitcnt lgkmcnt(0)" ::: "memory");
        __builtin_amdgcn_sched_barrier(0);
        __builtin_amdgcn_s_barrier();
        __builtin_amdgcn_sched_barrier(0);
        if (ks + 2 < NKS) STAGE(ks + 2, pb);
    }

    if (EPI == 2) {
        #pragma unroll
        for (int nt = 0; nt < 4; nt++) {
            int n = nb + wn2 + nt * 16 + lo;
            float s = 0.f;
            #pragma unroll
            for (int ot = 0; ot < 4; ot++)
                #pragma unroll
                for (int r = 0; r < 4; r++) {
                    int o = wo + ot * 16 + q * 4 + r;
                    float v = acc[ot][nt][r] + b2f(bias[o]);
                    v = gelu_f(v);
                    s += b2f(fc2w[o]) * v;
                }
            s += __shfl_xor(s, 16, 64);
            s += __shfl_xor(s, 32, 64);
            if (q == 0)
                psum[(size_t)(w & 1) * (Bb * Nn) + (size_t)b * Nn + n] = s;
        }
    } else {
        u16* tile = lds + w * 4352;   // 64n x 68 pitch
        #pragma unroll
        for (int nt = 0; nt < 4; nt++) {
            int n = nb + wn2 + nt * 16 + lo;
            float mv = b2f(mask[(size_t)b * Nn + n]);
            #pragma unroll
            for (int ot = 0; ot < 4; ot++) {
                u16 hv[4] __attribute__((aligned(8)));
                #pragma unroll
                for (int r = 0; r < 4; r++) {
                    int o = wo + ot * 16 + q * 4 + r;
                    float v = acc[ot][nt][r] + b2f(bias[o]) + f0p[b * Cc + o] * mv;
                    if (EPI == 0) v = gelu_f(v);
                    hv[r] = f2b(v);
                }
                *(uint2*)&tile[(nt * 16 + lo) * 68 + ot * 16 + q * 4] = *(const uint2*)hv;
            }
        }
        __syncthreads();
        #pragma unroll
        for (int it = 0; it < 8; it++) {
            int row = it * 8 + (lane >> 3), seg = lane & 7;
            uint4 v4 = *(const uint4*)&tile[row * 68 + seg * 8];
            *(uint4*)&h[((size_t)b * Nn + nb + wn2 + row) * 128 + wo + seg * 8] = v4;
        }
        if (EPI == 0) {
            // emit hw_cn[c][n] from the wave's 64n x 64o tile (c = wo+lane)
            int c = wo + lane;
            const u16* wnp = wn + (size_t)b * Nn + nb + wn2;
            u16* dstp = hw_cn + ((size_t)(b * Cc) + c) * Nn + nb + wn2;
            #pragma unroll
            for (int i = 0; i < 8; i++) {
                u16 hv8[8] __attribute__((aligned(16)));
                #pragma unroll
                for (int j2 = 0; j2 < 8; j2++) {
                    int nl2 = i * 8 + j2;
                    hv8[j2] = f2b(b2f(tile[nl2 * 68 + lane]) * b2f(wnp[nl2]));
                }
                *(uint4*)(dstp + i * 8) = *(const uint4*)hv8;
            }
        }
    }
}

// out = (psum0 + psum1 + fc2_b) * mask, dtype per flag
__global__ __launch_bounds__(256) void fc2_final(
    const float* __restrict__ psum, const u16* __restrict__ fc2b,
    const u16* __restrict__ mask, void* __restrict__ out, const int* __restrict__ flag) {
    int g = blockIdx.x * 256 + threadIdx.x;   // < Bb*Nn
    float s = psum[g] + psum[(size_t)Bb * Nn + g] + b2f(fc2b[0]);
    s *= b2f(mask[g]);
    if (*flag) ((u16*)out)[g] = f2b(s);
    else       ((float*)out)[g] = s;
}

extern "C" void kernel_launch(void* const* d_in, const int* in_sizes, int n_in,
                              void* d_out, int out_size, void* d_ws, size_t ws_size,
                              hipStream_t stream) {
    char* p = (char*)d_ws;
    auto alloc = [&](size_t bytes) { void* r = (void*)p; p += (bytes + 255) & ~(size_t)255; return r; };

    int* flag = (int*)alloc(256);

    SegTable tab;
    u16* nin[16];
    for (int i = 0; i < 16; i++) {
        tab.src[i] = d_in[i];
        if (i == 7 || i == 8) {
            nin[i] = (u16*)flag;
            tab.dst[i] = nin[i];
            tab.count[i] = 0;
        } else {
            int cnt = in_sizes[i];
            nin[i] = (u16*)alloc((size_t)cnt * 2);
            tab.dst[i] = nin[i];
            tab.count[i] = cnt;
        }
    }
    const u16* x      = nin[0];
    const u16* nodes  = nin[1];
    const u16* mask   = nin[2];
    const u16* wn     = nin[3];
    const u16* modes  = nin[4];
    const u16* fc0_w  = nin[5];
    const u16* fc0_b  = nin[6];
    const u16* w0n    = nin[9];
    const u16* conv_w = nin[10];
    const u16* conv_b = nin[11];
    const u16* fc1_w  = nin[12];
    const u16* fc1_b  = nin[13];
    const u16* fc2_w  = nin[14];
    const u16* fc2_b  = nin[15];

    u16* bigB   = (u16*)alloc((size_t)Bb * Nn * 256 * 2);        // 67.1 MB
    u16* hA     = (u16*)alloc((size_t)Bb * Nn * 128 * 2);        // 33.6 MB
    u16* hw_cn  = (u16*)alloc((size_t)Bb * Cc * Nn * 2);         // 33.6 MB
    u16* pxc    = (u16*)alloc((size_t)Bb * SPLIT * Cc * Kk * 2); // 8.4 MB
    u16* pps    = (u16*)alloc((size_t)Bb * SPLIT * Cc * Kk * 2); // 8.4 MB
    u16* wcT    = (u16*)alloc((size_t)Ll * Kk * Cc * Cc * 2);    // 16.8 MB
    u16* wsT    = (u16*)alloc((size_t)Ll * Kk * Cc * Cc * 2);    // 16.8 MB
    u16* w0T    = (u16*)alloc((size_t)Ll * Cc * Cc * 2);
    u16* xcT    = (u16*)alloc((size_t)Bb * Kk * Cc * 2);
    u16* psT    = (u16*)alloc((size_t)Bb * Kk * Cc * 2);
    u16* x0b    = (u16*)alloc((size_t)Bb * Cc * 2);
    float* f0f  = (float*)alloc((size_t)Bb * Cc * 4);
    u16* Ablk   = (u16*)alloc((size_t)Bb * 12 * 128 * 32 * 2);
    u16* Ablk1  = (u16*)alloc((size_t)4 * 128 * 32 * 2);
    float* psum = (float*)alloc((size_t)2 * Bb * Nn * 4);        // 1.0 MB
    // total ws ~= 190 MB

    const long ASTR = 12L * 128 * 32;

    detect_kernel<<<1, 64, 0, stream>>>((const unsigned int*)d_in[2], flag);
    convert_kernel<<<512, 256, 0, stream>>>(tab, flag);

    transpose_w<<<dim3(129, Ll), 256, 0, stream>>>(d_in[7], d_in[8], w0n, wcT, wsT, w0T, flag);
    prep_nk<<<dim3(Nn / 64, Bb), 256, 0, stream>>>(
        nodes, modes, mask, bigB, x, fc0_w, fc0_b, wn, hA, hw_cn);

    for (int l = 0; l < Ll; l++) {
        proj_mfma<<<dim3(SPLIT, 2, Bb), 256, 0, stream>>>(hw_cn, nodes, modes, mask, pxc, pps);
        reduce_kernel<<<dim3(512 + Bb * Cc), 256, 0, stream>>>(pxc, pps, xcT, psT, hw_cn, mask, x0b);
        mix_mfma<<<dim3(137), 256, 0, stream>>>(xcT, psT, wcT, wsT, w0T, x0b, conv_w, Ablk, f0f, l);
        if (l < Ll - 1) {
            combine_mfma<0, 12><<<dim3(Nn / 128, Bb), 256, 0, stream>>>(
                Ablk, ASTR, bigB, hA, hw_cn, f0f, conv_b + l * Cc, mask, wn, fc2_w, psum);
        } else {
            combine_mfma<1, 12><<<dim3(Nn / 128, Bb), 256, 0, stream>>>(
                Ablk, ASTR, bigB, hA, hw_cn, f0f, conv_b + l * Cc, mask, wn, fc2_w, psum);
        }
    }

    buildA1_blk<<<dim3(4), 256, 0, stream>>>(fc1_w, Ablk1);
    combine_mfma<2, 4><<<dim3(Nn / 128, Bb), 256, 0, stream>>>(
        Ablk1, 0L, bigB, hA, hw_cn, f0f, fc1_b, mask, wn, fc2_w, psum);
    fc2_final<<<dim3((Bb * Nn) / 256), 256, 0, stream>>>(psum, fc2_b, mask, d_out, flag);
}